// Round 11
// baseline (117.614 us; speedup 1.0000x reference)
//
#include <hip/hip_runtime.h>

#define D 64  // feature dim for all layers

#define NB 256   // level-1 edge-partition blocks
#define RB 256   // radix bins (dst>>8)
#define P2CAP 20 // register-cached records per thread in p2

__device__ inline float4 f4zero() { return make_float4(0.f, 0.f, 0.f, 0.f); }

// ---------------------------------------------------------------------------
// Shared gather core: 16 lanes per node (c = l4*4 channel quad), 8 independent
// accumulator chains -> 8 row-fetches in flight per lane-group. 4-deep and
// scalar tails keep low-degree nodes off the 1-deep cliff (R9 lesson).
// ---------------------------------------------------------------------------
__device__ __forceinline__ float4 gather_node(
    const float* __restrict__ H, const int2* __restrict__ pairs,
    int beg, int end, int c) {
  float4 A0 = f4zero(), A1 = f4zero(), A2 = f4zero(), A3 = f4zero();
  float4 A4 = f4zero(), A5 = f4zero(), A6 = f4zero(), A7 = f4zero();
  int i = beg;
  for (; i + 8 <= end; i += 8) {
    const int2 p0 = pairs[i],     p1 = pairs[i + 1];
    const int2 p2 = pairs[i + 2], p3 = pairs[i + 3];
    const int2 p4 = pairs[i + 4], p5 = pairs[i + 5];
    const int2 p6 = pairs[i + 6], p7 = pairs[i + 7];
    const float4 v0 = *reinterpret_cast<const float4*>(H + (size_t)p0.x * D + c);
    const float4 v1 = *reinterpret_cast<const float4*>(H + (size_t)p1.x * D + c);
    const float4 v2 = *reinterpret_cast<const float4*>(H + (size_t)p2.x * D + c);
    const float4 v3 = *reinterpret_cast<const float4*>(H + (size_t)p3.x * D + c);
    const float4 v4 = *reinterpret_cast<const float4*>(H + (size_t)p4.x * D + c);
    const float4 v5 = *reinterpret_cast<const float4*>(H + (size_t)p5.x * D + c);
    const float4 v6 = *reinterpret_cast<const float4*>(H + (size_t)p6.x * D + c);
    const float4 v7 = *reinterpret_cast<const float4*>(H + (size_t)p7.x * D + c);
    const float w0 = __int_as_float(p0.y), w1 = __int_as_float(p1.y);
    const float w2 = __int_as_float(p2.y), w3 = __int_as_float(p3.y);
    const float w4 = __int_as_float(p4.y), w5 = __int_as_float(p5.y);
    const float w6 = __int_as_float(p6.y), w7 = __int_as_float(p7.y);
    A0.x += w0 * v0.x; A0.y += w0 * v0.y; A0.z += w0 * v0.z; A0.w += w0 * v0.w;
    A1.x += w1 * v1.x; A1.y += w1 * v1.y; A1.z += w1 * v1.z; A1.w += w1 * v1.w;
    A2.x += w2 * v2.x; A2.y += w2 * v2.y; A2.z += w2 * v2.z; A2.w += w2 * v2.w;
    A3.x += w3 * v3.x; A3.y += w3 * v3.y; A3.z += w3 * v3.z; A3.w += w3 * v3.w;
    A4.x += w4 * v4.x; A4.y += w4 * v4.y; A4.z += w4 * v4.z; A4.w += w4 * v4.w;
    A5.x += w5 * v5.x; A5.y += w5 * v5.y; A5.z += w5 * v5.z; A5.w += w5 * v5.w;
    A6.x += w6 * v6.x; A6.y += w6 * v6.y; A6.z += w6 * v6.z; A6.w += w6 * v6.w;
    A7.x += w7 * v7.x; A7.y += w7 * v7.y; A7.z += w7 * v7.z; A7.w += w7 * v7.w;
  }
  if (i + 4 <= end) {
    const int2 p0 = pairs[i],     p1 = pairs[i + 1];
    const int2 p2 = pairs[i + 2], p3 = pairs[i + 3];
    const float4 v0 = *reinterpret_cast<const float4*>(H + (size_t)p0.x * D + c);
    const float4 v1 = *reinterpret_cast<const float4*>(H + (size_t)p1.x * D + c);
    const float4 v2 = *reinterpret_cast<const float4*>(H + (size_t)p2.x * D + c);
    const float4 v3 = *reinterpret_cast<const float4*>(H + (size_t)p3.x * D + c);
    const float w0 = __int_as_float(p0.y), w1 = __int_as_float(p1.y);
    const float w2 = __int_as_float(p2.y), w3 = __int_as_float(p3.y);
    A0.x += w0 * v0.x; A0.y += w0 * v0.y; A0.z += w0 * v0.z; A0.w += w0 * v0.w;
    A1.x += w1 * v1.x; A1.y += w1 * v1.y; A1.z += w1 * v1.z; A1.w += w1 * v1.w;
    A2.x += w2 * v2.x; A2.y += w2 * v2.y; A2.z += w2 * v2.z; A2.w += w2 * v2.w;
    A3.x += w3 * v3.x; A3.y += w3 * v3.y; A3.z += w3 * v3.z; A3.w += w3 * v3.w;
    i += 4;
  }
  for (; i < end; ++i) {
    const int2 p = pairs[i];
    const float4 v = *reinterpret_cast<const float4*>(H + (size_t)p.x * D + c);
    const float w = __int_as_float(p.y);
    A0.x += w * v.x; A0.y += w * v.y; A0.z += w * v.z; A0.w += w * v.w;
  }
  float4 r;
  r.x = ((A0.x + A1.x) + (A2.x + A3.x)) + ((A4.x + A5.x) + (A6.x + A7.x));
  r.y = ((A0.y + A1.y) + (A2.y + A3.y)) + ((A4.y + A5.y) + (A6.y + A7.y));
  r.z = ((A0.z + A1.z) + (A2.z + A3.z)) + ((A4.z + A5.z) + (A6.z + A7.z));
  r.w = ((A0.w + A1.w) + (A2.w + A3.w)) + ((A4.w + A5.w) + (A6.w + A7.w));
  return r;
}

// ---------------------------------------------------------------------------
// GEMM: out = f(A) @ W  (generic/fallback paths)
// ---------------------------------------------------------------------------
template <bool PRE>
__global__ __launch_bounds__(256, 4) void gemm64_kernel(
    const float* __restrict__ A, const float* __restrict__ W,
    const float* __restrict__ bpre, float* __restrict__ out, int N) {
  __shared__ float sA[64][68];
  __shared__ float sW[64][68];
  const int t = threadIdx.x;
  const int rowBase = blockIdx.x * 64;

#pragma unroll
  for (int i = t * 4; i < 4096; i += 1024) {
    const int k = i >> 6, c = i & 63;
    *reinterpret_cast<float4*>(&sW[k][c]) =
        *reinterpret_cast<const float4*>(W + i);
  }
#pragma unroll
  for (int i = t * 4; i < 4096; i += 1024) {
    const int r = i >> 6, k = i & 63;
    const int row = rowBase + r;
    float4 a = f4zero();
    if (row < N) a = *reinterpret_cast<const float4*>(A + (size_t)row * D + k);
    if (PRE) {
      const float4 b = *reinterpret_cast<const float4*>(bpre + k);
      a.x = fmaxf(a.x + b.x, 0.f);
      a.y = fmaxf(a.y + b.y, 0.f);
      a.z = fmaxf(a.z + b.z, 0.f);
      a.w = fmaxf(a.w + b.w, 0.f);
    }
    *reinterpret_cast<float4*>(&sA[r][k]) = a;
  }
  __syncthreads();

  const int ty = t >> 4, tx = t & 15;
  float4 acc0 = f4zero(), acc1 = f4zero(), acc2 = f4zero(), acc3 = f4zero();

#pragma unroll 4
  for (int kq = 0; kq < 16; ++kq) {
    const float4 w0 = *reinterpret_cast<const float4*>(&sW[kq * 4 + 0][tx * 4]);
    const float4 w1 = *reinterpret_cast<const float4*>(&sW[kq * 4 + 1][tx * 4]);
    const float4 w2 = *reinterpret_cast<const float4*>(&sW[kq * 4 + 2][tx * 4]);
    const float4 w3 = *reinterpret_cast<const float4*>(&sW[kq * 4 + 3][tx * 4]);
    const float4 a0 = *reinterpret_cast<const float4*>(&sA[ty * 4 + 0][kq * 4]);
    const float4 a1 = *reinterpret_cast<const float4*>(&sA[ty * 4 + 1][kq * 4]);
    const float4 a2 = *reinterpret_cast<const float4*>(&sA[ty * 4 + 2][kq * 4]);
    const float4 a3 = *reinterpret_cast<const float4*>(&sA[ty * 4 + 3][kq * 4]);
#define FMA4(ACC, AV)                                                     \
    ACC.x += AV.x * w0.x + AV.y * w1.x + AV.z * w2.x + AV.w * w3.x;       \
    ACC.y += AV.x * w0.y + AV.y * w1.y + AV.z * w2.y + AV.w * w3.y;       \
    ACC.z += AV.x * w0.z + AV.y * w1.z + AV.z * w2.z + AV.w * w3.z;       \
    ACC.w += AV.x * w0.w + AV.y * w1.w + AV.z * w2.w + AV.w * w3.w;
    FMA4(acc0, a0) FMA4(acc1, a1) FMA4(acc2, a2) FMA4(acc3, a3)
#undef FMA4
  }

  const int row0 = rowBase + ty * 4;
  if (row0 + 0 < N) *reinterpret_cast<float4*>(out + (size_t)(row0 + 0) * D + tx * 4) = acc0;
  if (row0 + 1 < N) *reinterpret_cast<float4*>(out + (size_t)(row0 + 1) * D + tx * 4) = acc1;
  if (row0 + 2 < N) *reinterpret_cast<float4*>(out + (size_t)(row0 + 2) * D + tx * 4) = acc2;
  if (row0 + 3 < N) *reinterpret_cast<float4*>(out + (size_t)(row0 + 3) * D + tx * 4) = acc3;
}

// ---------------------------------------------------------------------------
// MERGED kernel 1 (radix path): blocks [0,NB) coarse-histogram; rest gemm1.
// ---------------------------------------------------------------------------
__global__ __launch_bounds__(256, 4) void hist_gemm_kernel(
    const int* __restrict__ dst, int* __restrict__ countsB, int E, int epb,
    const float* __restrict__ A, const float* __restrict__ W,
    float* __restrict__ out, int N) {
  __shared__ float sA[64][68];
  __shared__ float sW[64][68];
  const int t = threadIdx.x;

  if ((int)blockIdx.x < NB) {
    int* h = reinterpret_cast<int*>(&sA[0][0]);
    h[t] = 0;
    __syncthreads();
    const int base = blockIdx.x * epb;
    const int lim = min(base + epb, E);
    for (int i = base + t; i < lim; i += 256) atomicAdd(&h[dst[i] >> 8], 1);
    __syncthreads();
    countsB[blockIdx.x * RB + t] = h[t];
    return;
  }

  const int rowBase = ((int)blockIdx.x - NB) * 64;
#pragma unroll
  for (int i = t * 4; i < 4096; i += 1024) {
    const int k = i >> 6, c = i & 63;
    *reinterpret_cast<float4*>(&sW[k][c]) =
        *reinterpret_cast<const float4*>(W + i);
  }
#pragma unroll
  for (int i = t * 4; i < 4096; i += 1024) {
    const int r = i >> 6, k = i & 63;
    const int row = rowBase + r;
    float4 a = f4zero();
    if (row < N) a = *reinterpret_cast<const float4*>(A + (size_t)row * D + k);
    *reinterpret_cast<float4*>(&sA[r][k]) = a;
  }
  __syncthreads();

  const int ty = t >> 4, tx = t & 15;
  float4 acc0 = f4zero(), acc1 = f4zero(), acc2 = f4zero(), acc3 = f4zero();

#pragma unroll 4
  for (int kq = 0; kq < 16; ++kq) {
    const float4 w0 = *reinterpret_cast<const float4*>(&sW[kq * 4 + 0][tx * 4]);
    const float4 w1 = *reinterpret_cast<const float4*>(&sW[kq * 4 + 1][tx * 4]);
    const float4 w2 = *reinterpret_cast<const float4*>(&sW[kq * 4 + 2][tx * 4]);
    const float4 w3 = *reinterpret_cast<const float4*>(&sW[kq * 4 + 3][tx * 4]);
    const float4 a0 = *reinterpret_cast<const float4*>(&sA[ty * 4 + 0][kq * 4]);
    const float4 a1 = *reinterpret_cast<const float4*>(&sA[ty * 4 + 1][kq * 4]);
    const float4 a2 = *reinterpret_cast<const float4*>(&sA[ty * 4 + 2][kq * 4]);
    const float4 a3 = *reinterpret_cast<const float4*>(&sA[ty * 4 + 3][kq * 4]);
#define FMA4(ACC, AV)                                                     \
    ACC.x += AV.x * w0.x + AV.y * w1.x + AV.z * w2.x + AV.w * w3.x;       \
    ACC.y += AV.x * w0.y + AV.y * w1.y + AV.z * w2.y + AV.w * w3.y;       \
    ACC.z += AV.x * w0.z + AV.y * w1.z + AV.z * w2.z + AV.w * w3.z;       \
    ACC.w += AV.x * w0.w + AV.y * w1.w + AV.z * w2.w + AV.w * w3.w;
    FMA4(acc0, a0) FMA4(acc1, a1) FMA4(acc2, a2) FMA4(acc3, a3)
#undef FMA4
  }

  const int row0 = rowBase + ty * 4;
  if (row0 + 0 < N) *reinterpret_cast<float4*>(out + (size_t)(row0 + 0) * D + tx * 4) = acc0;
  if (row0 + 1 < N) *reinterpret_cast<float4*>(out + (size_t)(row0 + 1) * D + tx * 4) = acc1;
  if (row0 + 2 < N) *reinterpret_cast<float4*>(out + (size_t)(row0 + 2) * D + tx * 4) = acc2;
  if (row0 + 3 < N) *reinterpret_cast<float4*>(out + (size_t)(row0 + 3) * D + tx * 4) = acc3;
}

// ---------------------------------------------------------------------------
// p1_scatter (radix): derives bin bases from block-major countsB, scatters
// records into coarse buckets. Block 0 publishes binBase[257] for p2.
// ---------------------------------------------------------------------------
__global__ __launch_bounds__(256) void p1_scatter_kernel(
    const int* __restrict__ src, const int* __restrict__ dst,
    const float* __restrict__ ew, const int* __restrict__ countsB,
    int* __restrict__ binBaseG, int2* __restrict__ tmp, int E, int epb) {
  __shared__ int s[RB];
  __shared__ int cur[RB];
  const int t = threadIdx.x;
  const int b = blockIdx.x;

  int total = 0, pre = 0;
#pragma unroll 8
  for (int i = 0; i < NB; ++i) {
    const int c = countsB[i * RB + t];
    if (i == b) pre = total;
    total += c;
  }
  s[t] = total;
  __syncthreads();
  for (int off = 1; off < 256; off <<= 1) {
    int x = (t >= off) ? s[t - off] : 0;
    __syncthreads();
    s[t] += x;
    __syncthreads();
  }
  const int binBase = s[t] - total;
  cur[t] = binBase + pre;
  if (b == 0) {
    binBaseG[t] = binBase;
    if (t == 255) binBaseG[256] = s[255];
  }
  __syncthreads();

  const int base = b * epb;
  const int lim = min(base + epb, E);
  for (int i = base + t; i < lim; i += 256) {
    const int d = dst[i];
    const unsigned sv = (unsigned)src[i];
    const float w = ew[i];
    const int pos = atomicAdd(&cur[d >> 8], 1);   // LDS atomic
    tmp[pos] = make_int2((int)((unsigned)d | (sv << 16)), __float_as_int(w));
  }
}

// ---------------------------------------------------------------------------
// p2 (radix): single global pass, register-cached records + ranks.
// ---------------------------------------------------------------------------
__global__ __launch_bounds__(256) void p2_kernel(
    const int2* __restrict__ tmp, const int* __restrict__ binBaseG,
    int* __restrict__ rankG,
    int* __restrict__ offs, int2* __restrict__ pairs, int N) {
  __shared__ int h[RB];
  __shared__ int s[RB];
  const int t = threadIdx.x;
  const int b = blockIdx.x;
  const int segBeg = binBaseG[b];
  const int segEnd = binBaseG[b + 1];
  const int segLen = segEnd - segBeg;

  h[t] = 0;
  __syncthreads();

  const int cnt = (segLen - t + 255) >> 8;   // my record count (>=0)
  int2 rec[P2CAP];
  int  rk[P2CAP];
#pragma unroll
  for (int k = 0; k < P2CAP; ++k) {
    if (k < cnt) {
      const int i = segBeg + t + (k << 8);
      const int2 r = tmp[i];
      rec[k] = r;
      rk[k] = atomicAdd(&h[r.x & 255], 1);
    }
  }
  for (int i = segBeg + (P2CAP << 8) + t; i < segEnd; i += 256)
    rankG[i] = atomicAdd(&h[tmp[i].x & 255], 1);   // overflow (rare)
  __syncthreads();

  const int v = h[t];
  s[t] = v;
  __syncthreads();
  for (int off = 1; off < 256; off <<= 1) {
    int x = (t >= off) ? s[t - off] : 0;
    __syncthreads();
    s[t] += x;
    __syncthreads();
  }
  const int excl = s[t] - v;
  const int node = b * RB + t;
  if (node <= N) offs[node] = segBeg + excl;
  __syncthreads();
  h[t] = segBeg + excl;     // reuse h as per-key base
  __syncthreads();

#pragma unroll
  for (int k = 0; k < P2CAP; ++k) {
    if (k < cnt) {
      const int2 r = rec[k];
      pairs[h[r.x & 255] + rk[k]] =
          make_int2((int)(((unsigned)r.x) >> 16), r.y);
    }
  }
  for (int i = segBeg + (P2CAP << 8) + t; i < segEnd; i += 256) {
    const int2 r = tmp[i];
    pairs[h[r.x & 255] + rankG[i]] =
        make_int2((int)(((unsigned)r.x) >> 16), r.y);
  }
}

// ---------------------------------------------------------------------------
// Generic CSR build (N > 65536): hist(+rank) atomics + scan trio + bucket
// ---------------------------------------------------------------------------
__global__ __launch_bounds__(256) void hist_kernel(
    const int* __restrict__ dst, int* __restrict__ deg,
    int* __restrict__ posw, int E) {
  int e = blockIdx.x * 256 + threadIdx.x;
  if (e < E) posw[e] = atomicAdd(&deg[dst[e]], 1);
}

#define SCAN_CHUNK 1024
__global__ __launch_bounds__(256) void scan_part_kernel(
    const int* __restrict__ deg, int* __restrict__ offs,
    int* __restrict__ bsums, int N) {
  __shared__ int s[256];
  const int t = threadIdx.x;
  const int base = blockIdx.x * SCAN_CHUNK + t * 4;
  int v0 = 0, v1 = 0, v2 = 0, v3 = 0;
  if (base + 3 < N) {
    const int4 v = *reinterpret_cast<const int4*>(deg + base);
    v0 = v.x; v1 = v.y; v2 = v.z; v3 = v.w;
  } else {
    if (base + 0 < N) v0 = deg[base + 0];
    if (base + 1 < N) v1 = deg[base + 1];
    if (base + 2 < N) v2 = deg[base + 2];
  }
  const int tsum = v0 + v1 + v2 + v3;
  s[t] = tsum;
  __syncthreads();
  for (int off = 1; off < 256; off <<= 1) {
    int x = (t >= off) ? s[t - off] : 0;
    __syncthreads();
    s[t] += x;
    __syncthreads();
  }
  const int excl = s[t] - tsum;
  if (base + 0 < N) offs[base + 0] = excl;
  if (base + 1 < N) offs[base + 1] = excl + v0;
  if (base + 2 < N) offs[base + 2] = excl + v0 + v1;
  if (base + 3 < N) offs[base + 3] = excl + v0 + v1 + v2;
  if (t == 255) bsums[blockIdx.x] = s[255];
}

__global__ __launch_bounds__(1024) void scan_sums_kernel(
    int* __restrict__ bsums, int* __restrict__ offsN, int nb) {
  __shared__ int s[1024];
  const int t = threadIdx.x;
  const int v = (t < nb) ? bsums[t] : 0;
  s[t] = v;
  __syncthreads();
  for (int off = 1; off < 1024; off <<= 1) {
    int x = (t >= off) ? s[t - off] : 0;
    __syncthreads();
    s[t] += x;
    __syncthreads();
  }
  if (t < nb) bsums[t] = s[t] - v;
  if (t == nb - 1) *offsN = s[t];
}

__global__ __launch_bounds__(256) void scan_add_kernel(
    int* __restrict__ offs, const int* __restrict__ bsums, int N) {
  const int i = blockIdx.x * 256 + threadIdx.x;
  if (i < N) offs[i] += bsums[i >> 10];
}

__global__ __launch_bounds__(256) void bucket_kernel(
    const int* __restrict__ src, const int* __restrict__ dst,
    const float* __restrict__ ew, const int* __restrict__ offs,
    const int* __restrict__ posw, int2* __restrict__ pairs, int E) {
  int e = blockIdx.x * 256 + threadIdx.x;
  if (e < E) {
    const int pos = offs[dst[e]] + posw[e];
    pairs[pos] = make_int2(src[e], __float_as_int(ew[e]));
  }
}

// ---------------------------------------------------------------------------
// FUSED: out[row] = relu(agg(H)[row] + b1) @ W  (8-deep gather + 64x64 gemm)
// ---------------------------------------------------------------------------
__global__ __launch_bounds__(256, 4) void agg_gemm_kernel(
    const float* __restrict__ H, const int* __restrict__ offs,
    const int2* __restrict__ pairs, const float* __restrict__ b1,
    const float* __restrict__ W, float* __restrict__ out, int N) {
  __shared__ float sA[64][68];
  __shared__ float sW[64][68];
  const int t = threadIdx.x;
  const int rowBase = blockIdx.x * 64;

#pragma unroll
  for (int i = t * 4; i < 4096; i += 1024) {
    const int k = i >> 6, c = i & 63;
    *reinterpret_cast<float4*>(&sW[k][c]) =
        *reinterpret_cast<const float4*>(W + i);
  }

  const int l4 = t & 15;
  const int sub = t >> 4;
  const float4 bb = *reinterpret_cast<const float4*>(b1 + l4 * 4);
#pragma unroll
  for (int p = 0; p < 4; ++p) {
    const int r = p * 16 + sub;
    const int node = rowBase + r;
    float4 a = f4zero();
    if (node < N) a = gather_node(H, pairs, offs[node], offs[node + 1], l4 * 4);
    float4 rr;
    rr.x = fmaxf(a.x + bb.x, 0.f);
    rr.y = fmaxf(a.y + bb.y, 0.f);
    rr.z = fmaxf(a.z + bb.z, 0.f);
    rr.w = fmaxf(a.w + bb.w, 0.f);
    *reinterpret_cast<float4*>(&sA[r][l4 * 4]) = rr;
  }
  __syncthreads();

  const int ty = t >> 4, tx = t & 15;
  float4 acc0 = f4zero(), acc1 = f4zero(), acc2 = f4zero(), acc3 = f4zero();

#pragma unroll 4
  for (int kq = 0; kq < 16; ++kq) {
    const float4 w0 = *reinterpret_cast<const float4*>(&sW[kq * 4 + 0][tx * 4]);
    const float4 w1 = *reinterpret_cast<const float4*>(&sW[kq * 4 + 1][tx * 4]);
    const float4 w2 = *reinterpret_cast<const float4*>(&sW[kq * 4 + 2][tx * 4]);
    const float4 w3 = *reinterpret_cast<const float4*>(&sW[kq * 4 + 3][tx * 4]);
    const float4 a0 = *reinterpret_cast<const float4*>(&sA[ty * 4 + 0][kq * 4]);
    const float4 a1 = *reinterpret_cast<const float4*>(&sA[ty * 4 + 1][kq * 4]);
    const float4 a2 = *reinterpret_cast<const float4*>(&sA[ty * 4 + 2][kq * 4]);
    const float4 a3 = *reinterpret_cast<const float4*>(&sA[ty * 4 + 3][kq * 4]);
#define FMA4(ACC, AV)                                                     \
    ACC.x += AV.x * w0.x + AV.y * w1.x + AV.z * w2.x + AV.w * w3.x;       \
    ACC.y += AV.x * w0.y + AV.y * w1.y + AV.z * w2.y + AV.w * w3.y;       \
    ACC.z += AV.x * w0.z + AV.y * w1.z + AV.z * w2.z + AV.w * w3.z;       \
    ACC.w += AV.x * w0.w + AV.y * w1.w + AV.z * w2.w + AV.w * w3.w;
    FMA4(acc0, a0) FMA4(acc1, a1) FMA4(acc2, a2) FMA4(acc3, a3)
#undef FMA4
  }

  const int row0 = rowBase + ty * 4;
  if (row0 + 0 < N) *reinterpret_cast<float4*>(out + (size_t)(row0 + 0) * D + tx * 4) = acc0;
  if (row0 + 1 < N) *reinterpret_cast<float4*>(out + (size_t)(row0 + 1) * D + tx * 4) = acc1;
  if (row0 + 2 < N) *reinterpret_cast<float4*>(out + (size_t)(row0 + 2) * D + tx * 4) = acc2;
  if (row0 + 3 < N) *reinterpret_cast<float4*>(out + (size_t)(row0 + 3) * D + tx * 4) = acc3;
}

// ---------------------------------------------------------------------------
// Gather-aggregate (final layer): 16 lanes/node, 8-deep chains.
// ---------------------------------------------------------------------------
template <bool BIAS>
__global__ __launch_bounds__(256, 4) void gather_agg_kernel(
    const float* __restrict__ H, const int* __restrict__ offs,
    const int2* __restrict__ pairs,
    const float* __restrict__ bias, float* __restrict__ out, int N) {
  const int l4 = threadIdx.x & 15;
  const int node = blockIdx.x * 16 + (threadIdx.x >> 4);
  if (node >= N) return;
  float4 r = gather_node(H, pairs, offs[node], offs[node + 1], l4 * 4);
  if (BIAS) {
    const float4 b = *reinterpret_cast<const float4*>(bias + l4 * 4);
    r.x += b.x; r.y += b.y; r.z += b.z; r.w += b.w;
  }
  *reinterpret_cast<float4*>(out + (size_t)node * D + l4 * 4) = r;
}

// ---------------------- fallback (atomic scatter) path ---------------------
__global__ __launch_bounds__(256) void scatter_kernel(
    const float* __restrict__ H, const float* __restrict__ ew,
    const int* __restrict__ src, const int* __restrict__ dst,
    float* __restrict__ out, int nEdges) {
  const int tid = blockIdx.x * 256 + threadIdx.x;
  const int e = tid >> 4;
  if (e >= nEdges) return;
  const int c = (tid & 15) * 4;
  const float w = ew[e];
  const float4 v = *reinterpret_cast<const float4*>(H + (size_t)src[e] * D + c);
  float* o = out + (size_t)dst[e] * D + c;
  atomicAdd(o + 0, w * v.x);
  atomicAdd(o + 1, w * v.y);
  atomicAdd(o + 2, w * v.z);
  atomicAdd(o + 3, w * v.w);
}

__global__ __launch_bounds__(256) void fill_bias_kernel(
    float* __restrict__ out, const float* __restrict__ b, int total) {
  int i = blockIdx.x * 256 + threadIdx.x;
  if (i < total) out[i] = b[i & 63];
}

// ---------------------------------------------------------------------------
extern "C" void kernel_launch(void* const* d_in, const int* in_sizes, int n_in,
                              void* d_out, int out_size, void* d_ws,
                              size_t ws_size, hipStream_t stream) {
  const float* X  = (const float*)d_in[0];
  const float* ew = (const float*)d_in[1];
  const float* W1 = (const float*)d_in[2];
  const float* b1 = (const float*)d_in[3];
  const float* W2 = (const float*)d_in[4];
  const float* b2 = (const float*)d_in[5];
  const int*   ei = (const int*)d_in[6];

  const int N = in_sizes[0] / D;   // 50000
  const int E = in_sizes[6] / 2;   // 800000
  const int* src = ei;
  const int* dst = ei + E;
  float* out = (float*)d_out;

  // workspace layout
  char* ws = (char*)d_ws;
  float* buf0 = (float*)ws;                 ws += (size_t)N * D * 4;
  float* buf1 = (float*)ws;                 ws += (size_t)N * D * 4;
  const size_t baseBytes = (size_t)(ws - (char*)d_ws);
  int2*  pairs    = (int2*)ws;              ws += (size_t)E * 8;
  int*   offs     = (int*)ws;               ws += (size_t)(N + 1) * 4;
  int*   countsB  = (int*)ws;               ws += (size_t)NB * RB * 4;
  int*   binBaseG = (int*)ws;               ws += (size_t)(RB + 1) * 4;
  int*   rankG    = (int*)ws;               ws += (size_t)E * 4;
  const size_t needBytes = (size_t)(ws - (char*)d_ws);

  const int gemmBlocks = (N + 63) / 64;
  const int aggBlocks  = (N + 15) / 16;
  const int edgeBlocks = (E + 255) / 256;

  if (ws_size >= needBytes) {
    if (N <= NB * RB && (size_t)N * D * 4 >= (size_t)E * 8) {
      // ---- radix build merged with gemm1: no global atomics ----
      int2* tmp = (int2*)buf1;   // buf1 dead until agg_gemm writes it
      const int epb = (E + NB - 1) / NB;
      hist_gemm_kernel<<<NB + gemmBlocks, 256, 0, stream>>>(
          dst, countsB, E, epb, X, W1, buf0, N);
      p1_scatter_kernel<<<NB, 256, 0, stream>>>(src, dst, ew, countsB,
                                                binBaseG, tmp, E, epb);
      p2_kernel<<<RB, 256, 0, stream>>>(tmp, binBaseG, rankG, offs, pairs, N);
    } else {
      // ---- generic build + separate gemm1 ----
      int* deg   = (int*)buf0;
      int* bsums = (int*)buf0 + N;
      int* posw  = (int*)buf1;
      const int nb = (N + SCAN_CHUNK - 1) / SCAN_CHUNK;
      hipMemsetAsync(deg, 0, (size_t)N * 4, stream);
      hist_kernel<<<edgeBlocks, 256, 0, stream>>>(dst, deg, posw, E);
      scan_part_kernel<<<nb, 256, 0, stream>>>(deg, offs, bsums, N);
      scan_sums_kernel<<<1, 1024, 0, stream>>>(bsums, offs + N, nb);
      scan_add_kernel<<<(N + 255) / 256, 256, 0, stream>>>(offs, bsums, N);
      bucket_kernel<<<edgeBlocks, 256, 0, stream>>>(src, dst, ew, offs, posw, pairs, E);
      gemm64_kernel<false><<<gemmBlocks, 256, 0, stream>>>(X, W1, nullptr, buf0, N);
    }

    // ---- fused(agg+relu+gemm2) -> final gather ----
    agg_gemm_kernel<<<gemmBlocks, 256, 0, stream>>>(buf0, offs, pairs, b1, W2, buf1, N);
    gather_agg_kernel<true><<<aggBlocks, 256, 0, stream>>>(buf1, offs, pairs, b2, out, N);
  } else if (ws_size >= baseBytes) {
    // ---- fallback: atomic scatter (slow but correct) ----
    const int scatBlocks = (E * 16 + 255) / 256;
    const int fillBlocks = (N * D + 255) / 256;
    gemm64_kernel<false><<<gemmBlocks, 256, 0, stream>>>(X, W1, nullptr, buf0, N);
    hipMemsetAsync(buf1, 0, (size_t)N * D * 4, stream);
    scatter_kernel<<<scatBlocks, 256, 0, stream>>>(buf0, ew, src, dst, buf1, E);
    gemm64_kernel<true><<<gemmBlocks, 256, 0, stream>>>(buf1, W2, b1, buf0, N);
    fill_bias_kernel<<<fillBlocks, 256, 0, stream>>>(out, b2, N * D);
    scatter_kernel<<<scatBlocks, 256, 0, stream>>>(buf0, ew, src, dst, out, E);
  }
}